// Round 3
// baseline (34955.560 us; speedup 1.0000x reference)
//
#include <hip/hip_runtime.h>
#include <hip/hip_bf16.h>
#include <cstdint>
#include <cstddef>
#include <type_traits>

// Problem: 2-layer LSTM, B=32, T=2048, D=H=512, 4H=2048.
// Inputs fp32; OUTPUT fp32 (harness reads np.float32; threshold is
// bf16-floored so bf16 MFMA compute is allowed). c state fp32.
//
// ws layout (bytes):
//   i2h  [T][B][4H] bf16 : off 0,          size 268435456
//   y0   [B][T][H]  bf16 : off 268435456,  size 67108864
//   Whb0 [2048][512] bf16: off 335544320,  size 2097152
//   Whb1 [2048][512] bf16: off 337641472,  size 2097152
//   h0a  [B][H]     bf16 : off 339738624,  size 32768
//   h0b                  : off 339771392
//   h1a                  : off 339804160
//   h1b                  : off 339836928
//   c0   [B][H]     f32  : off 339869696,  size 65536
//   c1                   : off 339935232
// total ~340 MB

typedef __attribute__((ext_vector_type(8))) short short8;   // 8 x bf16
typedef __attribute__((ext_vector_type(4))) short short4v;  // 4 x bf16
typedef __attribute__((ext_vector_type(4))) float f32x4;
typedef __attribute__((ext_vector_type(4))) int int4v;

#define MFMA_BF16_16x16x32(A_, B_, C_) \
    __builtin_amdgcn_mfma_f32_16x16x32_bf16(A_, B_, C_, 0, 0, 0)

__device__ __forceinline__ short f2bf(float f) {
    __hip_bfloat16 b = __float2bfloat16(f);
    return *reinterpret_cast<short*>(&b);
}

// ---------------------------------------------------------------------------
// fp32 -> bf16 elementwise convert (for Wh weights), one float4 per thread.
// ---------------------------------------------------------------------------
__global__ __launch_bounds__(256) void cvt_f32_bf16(
    const float* __restrict__ in, __hip_bfloat16* __restrict__ outp)
{
    const int i = blockIdx.x * 256 + threadIdx.x;
    const float4 v = ((const float4*)in)[i];
    short4v o;
    o[0] = f2bf(v.x); o[1] = f2bf(v.y); o[2] = f2bf(v.z); o[3] = f2bf(v.w);
    ((short4v*)outp)[i] = o;
}

// ---------------------------------------------------------------------------
// i2h GEMM: C[(t*32+b)][n] = sum_k A[m][k] * W[n][k] + bi[n] + bh[n]
// A: [M=65536, K=512] row-major, dtype AT (float for layer0, bf16 for layer1)
//    (m = b*2048 + t)
// W: [N=2048, K=512] fp32 row-major, converted to bf16 during staging
// out: [T][B][N] bf16  (index (t*32+b)*N + n)
// 128x128 tile, BK=32, 256 threads (4 waves, 2x2 wave quadrants of 64x64)
// ---------------------------------------------------------------------------
template <typename AT>
__global__ __launch_bounds__(256) void lstm_gemm_i2h(
    const AT* __restrict__ A,
    const float* __restrict__ W,
    const float* __restrict__ bi,
    const float* __restrict__ bh,
    __hip_bfloat16* __restrict__ out)
{
    constexpr int K = 512;
    constexpr int N = 2048;
    const int tid  = threadIdx.x;
    const int lane = tid & 63;
    const int w    = tid >> 6;
    const int wm   = w >> 1, wn = w & 1;
    const int quad = lane >> 4, l15 = lane & 15;
    const int m0 = blockIdx.y * 128;
    const int n0 = blockIdx.x * 128;

    __shared__ __align__(16) short sA[128 * 32];
    __shared__ __align__(16) short sB[128 * 32];

    f32x4 acc[4][4] = {};

    // fp32 staging coords: 2 threads per row, 16 floats each
    const int frow = tid >> 1;         // 0..127
    const int fcol = (tid & 1) * 16;   // 0 or 16
    // bf16 staging coords: 4 threads per row, 8 shorts each, 2 rows/thread
    const int brow = tid >> 2;         // 0..63
    const int bcol = (tid & 3) * 8;    // 0,8,16,24

    for (int k0 = 0; k0 < K; k0 += 32) {
        __syncthreads();
        // ---- stage A ----
        if constexpr (std::is_same<AT, float>::value) {
            const float* ap = A + (size_t)(m0 + frow) * K + k0 + fcol;
            float4 v0 = ((const float4*)ap)[0];
            float4 v1 = ((const float4*)ap)[1];
            float4 v2 = ((const float4*)ap)[2];
            float4 v3 = ((const float4*)ap)[3];
            short8 lo, hi;
            lo[0]=f2bf(v0.x); lo[1]=f2bf(v0.y); lo[2]=f2bf(v0.z); lo[3]=f2bf(v0.w);
            lo[4]=f2bf(v1.x); lo[5]=f2bf(v1.y); lo[6]=f2bf(v1.z); lo[7]=f2bf(v1.w);
            hi[0]=f2bf(v2.x); hi[1]=f2bf(v2.y); hi[2]=f2bf(v2.z); hi[3]=f2bf(v2.w);
            hi[4]=f2bf(v3.x); hi[5]=f2bf(v3.y); hi[6]=f2bf(v3.z); hi[7]=f2bf(v3.w);
            *(short8*)&sA[frow * 32 + fcol]     = lo;
            *(short8*)&sA[frow * 32 + fcol + 8] = hi;
        } else {
            const int4v a0 = *(const int4v*)((const short*)A + (size_t)(m0 + brow) * K + k0 + bcol);
            const int4v a1 = *(const int4v*)((const short*)A + (size_t)(m0 + brow + 64) * K + k0 + bcol);
            *(int4v*)&sA[brow * 32 + bcol]        = a0;
            *(int4v*)&sA[(brow + 64) * 32 + bcol] = a1;
        }
        // ---- stage W (always fp32 -> bf16) ----
        {
            const float* wp = W + (size_t)(n0 + frow) * K + k0 + fcol;
            float4 v0 = ((const float4*)wp)[0];
            float4 v1 = ((const float4*)wp)[1];
            float4 v2 = ((const float4*)wp)[2];
            float4 v3 = ((const float4*)wp)[3];
            short8 lo, hi;
            lo[0]=f2bf(v0.x); lo[1]=f2bf(v0.y); lo[2]=f2bf(v0.z); lo[3]=f2bf(v0.w);
            lo[4]=f2bf(v1.x); lo[5]=f2bf(v1.y); lo[6]=f2bf(v1.z); lo[7]=f2bf(v1.w);
            hi[0]=f2bf(v2.x); hi[1]=f2bf(v2.y); hi[2]=f2bf(v2.z); hi[3]=f2bf(v2.w);
            hi[4]=f2bf(v3.x); hi[5]=f2bf(v3.y); hi[6]=f2bf(v3.z); hi[7]=f2bf(v3.w);
            *(short8*)&sB[frow * 32 + fcol]     = lo;
            *(short8*)&sB[frow * 32 + fcol + 8] = hi;
        }
        __syncthreads();

        short8 aF[4], bF[4];
        #pragma unroll
        for (int i = 0; i < 4; ++i) {
            aF[i] = *(const short8*)&sA[(wm * 64 + i * 16 + l15) * 32 + quad * 8];
            bF[i] = *(const short8*)&sB[(wn * 64 + i * 16 + l15) * 32 + quad * 8];
        }
        #pragma unroll
        for (int mi = 0; mi < 4; ++mi)
            #pragma unroll
            for (int ni = 0; ni < 4; ++ni)
                acc[mi][ni] = MFMA_BF16_16x16x32(aF[mi], bF[ni], acc[mi][ni]);
    }

    // epilogue: D row = quad*4 + r (m), col = l15 (n); scatter m -> (t*32+b)
    #pragma unroll
    for (int ni = 0; ni < 4; ++ni) {
        const int n = n0 + wn * 64 + ni * 16 + l15;
        const float bias = bi[n] + bh[n];
        #pragma unroll
        for (int mi = 0; mi < 4; ++mi) {
            #pragma unroll
            for (int r = 0; r < 4; ++r) {
                const int m = m0 + wm * 64 + mi * 16 + quad * 4 + r;
                const int b = m >> 11;      // m / 2048
                const int t = m & 2047;     // m % 2048
                out[(size_t)(t * 32 + b) * N + n] = __float2bfloat16(acc[mi][ni][r] + bias);
            }
        }
    }
}

// ---------------------------------------------------------------------------
// One LSTM timestep: gates = i2h_t + hin @ Wh^T (bias already folded in i2h),
// then elementwise -> hout, c, y[:, t, :].
// Grid: 32 blocks x 256 thr. Block j owns h-columns [j*16, j*16+16).
// Wave = gate (i,f,g,o). Each wave: 2 m-tiles (b 0-15, 16-31), K=512.
// YT = bf16 (layer 0 -> ws) or float (layer 1 -> d_out).
// ---------------------------------------------------------------------------
template <typename YT>
__global__ __launch_bounds__(256) void lstm_step(
    const __hip_bfloat16* __restrict__ i2h_t,  // [32][2048]
    const __hip_bfloat16* __restrict__ Wh,     // [2048][512] bf16 (pre-converted)
    const __hip_bfloat16* __restrict__ hin,    // [32][512]
    __hip_bfloat16* __restrict__ hout,         // [32][512]
    float* __restrict__ c,                     // [32][512]
    YT* __restrict__ y,                        // [B][T][H] base
    int t)
{
    constexpr int K = 512;
    const int tid  = threadIdx.x;
    const int lane = tid & 63;
    const int gate = tid >> 6;
    const int quad = lane >> 4, l15 = lane & 15;
    const int col0 = blockIdx.x * 16;

    f32x4 acc0 = {}, acc1 = {};
    const __hip_bfloat16* wrow = Wh + (size_t)(gate * 512 + col0 + l15) * K + quad * 8;
    const __hip_bfloat16* ha = hin + (size_t)l15 * K + quad * 8;
    const __hip_bfloat16* hb = hin + (size_t)(16 + l15) * K + quad * 8;

    #pragma unroll
    for (int kk = 0; kk < 16; ++kk) {
        const short8 bF = *(const short8*)(wrow + kk * 32);
        const short8 a0 = *(const short8*)(ha + kk * 32);
        const short8 a1 = *(const short8*)(hb + kk * 32);
        acc0 = MFMA_BF16_16x16x32(a0, bF, acc0);
        acc1 = MFMA_BF16_16x16x32(a1, bF, acc1);
    }

    __shared__ float gl[4][32][16];
    #pragma unroll
    for (int r = 0; r < 4; ++r) {
        gl[gate][quad * 4 + r][l15]      = acc0[r];
        gl[gate][16 + quad * 4 + r][l15] = acc1[r];
    }
    __syncthreads();

    const int col = tid & 15;
    const int b0  = tid >> 4;  // 0..15
    #pragma unroll
    for (int half = 0; half < 2; ++half) {
        const int b  = b0 + half * 16;
        const int cg = col0 + col;
        float iv = gl[0][b][col] + __bfloat162float(i2h_t[b * 2048 + 0 * 512 + cg]);
        float fv = gl[1][b][col] + __bfloat162float(i2h_t[b * 2048 + 1 * 512 + cg]);
        float gv = gl[2][b][col] + __bfloat162float(i2h_t[b * 2048 + 2 * 512 + cg]);
        float ov = gl[3][b][col] + __bfloat162float(i2h_t[b * 2048 + 3 * 512 + cg]);
        const float ig = 1.f / (1.f + __expf(-iv));
        const float fg = 1.f / (1.f + __expf(-fv));
        const float gg = 1.f - 2.f / (__expf(2.f * gv) + 1.f);
        const float og = 1.f / (1.f + __expf(-ov));
        const float cp = c[b * 512 + cg];
        const float cn = fg * cp + ig * gg;
        const float hn = og * (1.f - 2.f / (__expf(2.f * cn) + 1.f));
        c[b * 512 + cg] = cn;
        hout[b * 512 + cg] = __float2bfloat16(hn);
        if constexpr (std::is_same<YT, float>::value) {
            y[(size_t)b * (2048 * 512) + (size_t)t * 512 + cg] = hn;
        } else {
            y[(size_t)b * (2048 * 512) + (size_t)t * 512 + cg] = __float2bfloat16(hn);
        }
    }
}

// ---------------------------------------------------------------------------
// Copy final h/c of both layers into d_out tail (fp32).
// Tail layout (fp32 elems, rel. to out+33554432):
//   h[0] at 0..16383, h[1] at 16384..32767, c[0] at 32768..49151, c[1] at 49152..
// ---------------------------------------------------------------------------
__global__ __launch_bounds__(256) void lstm_copy_finals(
    const __hip_bfloat16* __restrict__ h0, const __hip_bfloat16* __restrict__ h1,
    const float* __restrict__ c0, const float* __restrict__ c1,
    float* __restrict__ out)
{
    const int i = blockIdx.x * 256 + threadIdx.x;  // 0..16383
    out[i]         = __bfloat162float(h0[i]);
    out[16384 + i] = __bfloat162float(h1[i]);
    out[32768 + i] = c0[i];
    out[49152 + i] = c1[i];
}

extern "C" void kernel_launch(void* const* d_in, const int* in_sizes, int n_in,
                              void* d_out, int out_size, void* d_ws, size_t ws_size,
                              hipStream_t stream)
{
    const float* x   = (const float*)d_in[0];
    const float* Wi0 = (const float*)d_in[1];
    const float* bi0 = (const float*)d_in[2];
    const float* Wh0 = (const float*)d_in[3];
    const float* bh0 = (const float*)d_in[4];
    const float* Wi1 = (const float*)d_in[5];
    const float* bi1 = (const float*)d_in[6];
    const float* Wh1 = (const float*)d_in[7];
    const float* bh1 = (const float*)d_in[8];
    float* out = (float*)d_out;

    char* ws = (char*)d_ws;
    __hip_bfloat16* i2h  = (__hip_bfloat16*)(ws);
    __hip_bfloat16* y0   = (__hip_bfloat16*)(ws + 268435456ULL);
    __hip_bfloat16* Whb0 = (__hip_bfloat16*)(ws + 335544320ULL);
    __hip_bfloat16* Whb1 = (__hip_bfloat16*)(ws + 337641472ULL);
    __hip_bfloat16* h0a  = (__hip_bfloat16*)(ws + 339738624ULL);
    __hip_bfloat16* h0b  = (__hip_bfloat16*)(ws + 339771392ULL);
    __hip_bfloat16* h1a  = (__hip_bfloat16*)(ws + 339804160ULL);
    __hip_bfloat16* h1b  = (__hip_bfloat16*)(ws + 339836928ULL);
    float*          c0   = (float*)(ws + 339869696ULL);
    float*          c1   = (float*)(ws + 339935232ULL);

    // zero initial state (ws is poisoned 0xAA before every call)
    hipMemsetAsync(h0a, 0, 32768, stream);
    hipMemsetAsync(h0b, 0, 32768, stream);
    hipMemsetAsync(h1a, 0, 32768, stream);
    hipMemsetAsync(h1b, 0, 32768, stream);
    hipMemsetAsync(c0, 0, 65536, stream);
    hipMemsetAsync(c1, 0, 65536, stream);

    // pre-convert Wh weights to bf16 (1048576 elems each = 262144 float4s)
    cvt_f32_bf16<<<1024, 256, 0, stream>>>(Wh0, Whb0);
    cvt_f32_bf16<<<1024, 256, 0, stream>>>(Wh1, Whb1);

    const dim3 ggrid(16, 512);  // N/128, M/128

    // ---- layer 0 ----
    lstm_gemm_i2h<float><<<ggrid, 256, 0, stream>>>(x, Wi0, bi0, bh0, i2h);
    for (int t = 0; t < 2048; ++t) {
        lstm_step<__hip_bfloat16><<<32, 256, 0, stream>>>(
            i2h + (size_t)t * 32 * 2048, Whb0,
            (t & 1) ? h0b : h0a, (t & 1) ? h0a : h0b,
            c0, y0, t);
    }

    // ---- layer 1 ----
    lstm_gemm_i2h<__hip_bfloat16><<<ggrid, 256, 0, stream>>>(y0, Wi1, bi1, bh1, i2h);
    for (int t = 0; t < 2048; ++t) {
        lstm_step<float><<<32, 256, 0, stream>>>(
            i2h + (size_t)t * 32 * 2048, Whb1,
            (t & 1) ? h1b : h1a, (t & 1) ? h1a : h1b,
            c1, out, t);
    }

    // final (h, c): after t=2047 (odd), last write went to the 'a' buffers
    lstm_copy_finals<<<64, 256, 0, stream>>>(h0a, h1a, c0, c1, out + 33554432ULL);
}